// Round 1
// baseline (367.942 us; speedup 1.0000x reference)
//
#include <hip/hip_runtime.h>

#define LBL 64
#define SEQN 512
#define BATCHN 512
#define START_ID 62
#define PAD_ID 63

// One block per batch element, 64 threads = 1 wave. Lane j owns label-state j.
// Linear-space forward recurrence: A <- (A . expT) * exp(e), renorm every 4 steps.
__global__ __launch_bounds__(64) void crf_batch_kernel(
    const float* __restrict__ ts,      // [B,S,L] tag_scores
    const float* __restrict__ T,       // [L,L]
    const int*   __restrict__ labels,  // [B,S]
    const int*   __restrict__ lengths, // [B]
    float*       __restrict__ ws)      // [B] out: fwd_b - gold_b
{
  const int b = blockIdx.x;
  const int j = threadIdx.x;  // 0..63
  const int len = lengths[b];
  const float* __restrict__ e_b = ts + (size_t)b * SEQN * LBL;
  const int* __restrict__ lab_b = labels + b * SEQN;

  __shared__ __align__(16) float p_lds[LBL];

  // Preload expT column j into registers: c[i] = exp(T[i][j]).
  // Per-i the 64 lanes read contiguous T[i*64 + j] -> coalesced.
  float c[LBL];
#pragma unroll
  for (int i = 0; i < LBL; ++i) c[i] = __expf(T[i * LBL + j]);
  const float expPad = __expf(T[j * LBL + PAD_ID]);  // exp(T[j, PAD])

  // alpha0 in linear space
  float A = __expf(e_b[j] + T[START_ID * LBL + j]);
  float logoff = 0.0f;

  // Prefetch emissions 4 steps ahead (clamped; reads stay in-buffer).
  float epf0, epf1, epf2, epf3;
  {
    int t1 = (1 < SEQN) ? 1 : SEQN - 1;
    int t2 = (2 < SEQN) ? 2 : SEQN - 1;
    int t3 = (3 < SEQN) ? 3 : SEQN - 1;
    int t4 = (4 < SEQN) ? 4 : SEQN - 1;
    epf0 = e_b[t1 * LBL + j];
    epf1 = e_b[t2 * LBL + j];
    epf2 = e_b[t3 * LBL + j];
    epf3 = e_b[t4 * LBL + j];
  }

  for (int t = 1; t < len; ++t) {
    p_lds[j] = A;
    __syncthreads();  // single-wave: compiler elides s_barrier, keeps ordering

    float e = epf0;
    epf0 = epf1; epf1 = epf2; epf2 = epf3;
    int tn = t + 4; tn = (tn > SEQN - 1) ? (SEQN - 1) : tn;
    epf3 = e_b[tn * LBL + j];

    float s0 = 0.f, s1 = 0.f, s2 = 0.f, s3 = 0.f;
#pragma unroll
    for (int i = 0; i < LBL; i += 4) {
      float4 pv = *(const float4*)(p_lds + i);  // same-addr broadcast read
      s0 = fmaf(pv.x, c[i + 0], s0);
      s1 = fmaf(pv.y, c[i + 1], s1);
      s2 = fmaf(pv.z, c[i + 2], s2);
      s3 = fmaf(pv.w, c[i + 3], s3);
    }
    A = ((s0 + s1) + (s2 + s3)) * __expf(e);
    __syncthreads();  // WAR guard before next iteration's p_lds write

    if ((t & 3) == 0) {
      float m = A;
#pragma unroll
      for (int d = 1; d < 64; d <<= 1) m = fmaxf(m, __shfl_xor(m, d));
      A = A / m;
      logoff += __logf(m);
    }
  }

  // ---- gold path score (lane-strided over t) ----
  float g = 0.0f;
  for (int t = j; t < len; t += 64) {
    int l = lab_b[t];
    int prev = (t == 0) ? START_ID : lab_b[t - 1];
    g += T[prev * LBL + l] + e_b[t * LBL + l];
  }

  // ---- final logsumexp + wave reductions ----
  float v = A * expPad;
#pragma unroll
  for (int d = 1; d < 64; d <<= 1) {
    v += __shfl_xor(v, d);
    g += __shfl_xor(g, d);
  }

  if (j == 0) {
    int last = lab_b[len - 1];
    float gold = g + T[last * LBL + PAD_ID];
    ws[b] = (logoff + __logf(v)) - gold;
  }
}

__global__ __launch_bounds__(256) void crf_reduce_kernel(
    const float* __restrict__ ws, float* __restrict__ out)
{
  __shared__ float red[4];
  int tid = threadIdx.x;  // 256 threads
  float v = ws[tid] + ws[tid + 256];
#pragma unroll
  for (int d = 1; d < 64; d <<= 1) v += __shfl_xor(v, d);
  if ((tid & 63) == 0) red[tid >> 6] = v;
  __syncthreads();
  if (tid == 0) out[0] = (red[0] + red[1] + red[2] + red[3]) * (1.0f / BATCHN);
}

extern "C" void kernel_launch(void* const* d_in, const int* in_sizes, int n_in,
                              void* d_out, int out_size, void* d_ws, size_t ws_size,
                              hipStream_t stream) {
  const float* ts      = (const float*)d_in[0];
  const float* T       = (const float*)d_in[1];
  const int*   labels  = (const int*)d_in[2];
  const int*   lengths = (const int*)d_in[3];
  float* out = (float*)d_out;
  float* ws  = (float*)d_ws;

  crf_batch_kernel<<<BATCHN, 64, 0, stream>>>(ts, T, labels, lengths, ws);
  crf_reduce_kernel<<<1, 256, 0, stream>>>(ws, out);
}

// Round 2
// 253.698 us; speedup vs baseline: 1.4503x; 1.4503x over previous
//
#include <hip/hip_runtime.h>

#define LBL 64
#define SEQN 512
#define BATCHN 512
#define START_ID 62
#define PAD_ID 63
#define CH 8            // steps per chunk (emission prefetch distance = 8..16 steps)
#define NCH (SEQN / CH)

// One block per batch element, 64 threads = 1 wave. Lane j owns label-state j.
// Linear-space recurrence A <- (A . expT) * exp(e). Broadcast of A via
// v_readlane (SGPR), renorm via SALU integer-max on f32 bits (exact 2^k scale).
__global__ __launch_bounds__(64) void crf_batch_kernel(
    const float* __restrict__ ts,      // [B,S,L]
    const float* __restrict__ T,       // [L,L]
    const int*   __restrict__ labels,  // [B,S]
    const int*   __restrict__ lengths, // [B]
    float*       __restrict__ ws)      // [B] out: fwd_b - gold_b
{
  const int b = blockIdx.x;
  const int j = threadIdx.x;  // 0..63
  const int len = lengths[b];
  const float* __restrict__ e_b = ts + (size_t)b * SEQN * LBL;
  const int* __restrict__ lab_b = labels + b * SEQN;

  // expT column j in registers: c[i] = exp(T[i][j]). Coalesced loads.
  float c[LBL];
#pragma unroll
  for (int i = 0; i < LBL; ++i) c[i] = __expf(T[i * LBL + j]);
  const float expPad = __expf(T[j * LBL + PAD_ID]);  // exp(T[j, PAD])

  // Emission double-buffer: chunk c0 in eC, chunk c0+1 in eN. All static idx.
  float eC[CH], eN[CH];
#pragma unroll
  for (int r = 0; r < CH; ++r) eC[r] = e_b[r * LBL + j];
#pragma unroll
  for (int r = 0; r < CH; ++r) eN[r] = e_b[(CH + r) * LBL + j];

  float A = __expf(eC[0] + T[START_ID * LBL + j]);  // alpha0, linear space
  int E = 0;  // accumulated power-of-2 exponent shifts: A_stored = A_true * 2^E

  for (int c0 = 0; c0 < NCH; ++c0) {
    const int t0 = c0 * CH;
    if (t0 >= len) break;

#pragma unroll
    for (int tt = 0; tt < CH; ++tt) {
      const int t = t0 + tt;
      if (t >= 1 && t < len) {
        const int Abits = __float_as_int(A);
        unsigned mx = 0u;
        float s0 = 0.f, s1 = 0.f, s2 = 0.f, s3 = 0.f;
#pragma unroll
        for (int k = 0; k < 16; ++k) {
          const float a0 = __int_as_float(__builtin_amdgcn_readlane(Abits, k));
          const float a1 = __int_as_float(__builtin_amdgcn_readlane(Abits, k + 16));
          const float a2 = __int_as_float(__builtin_amdgcn_readlane(Abits, k + 32));
          const float a3 = __int_as_float(__builtin_amdgcn_readlane(Abits, k + 48));
          s0 = fmaf(a0, c[k], s0);
          s1 = fmaf(a1, c[k + 16], s1);
          s2 = fmaf(a2, c[k + 32], s2);
          s3 = fmaf(a3, c[k + 48], s3);
          if ((tt & 3) == 0) {  // static: renorm steps fold a SALU umax tree
            unsigned u0 = (unsigned)__float_as_uint(a0);
            unsigned u1 = (unsigned)__float_as_uint(a1);
            unsigned u2 = (unsigned)__float_as_uint(a2);
            unsigned u3 = (unsigned)__float_as_uint(a3);
            unsigned m01 = u0 > u1 ? u0 : u1;
            unsigned m23 = u2 > u3 ? u2 : u3;
            unsigned m = m01 > m23 ? m01 : m23;
            mx = mx > m ? mx : m;
          }
        }
        const float sum = (s0 + s1) + (s2 + s3);
        float ex = __expf(eC[tt]);
        if ((tt & 3) == 0) {
          const int em = (int)(mx >> 23);          // max exponent of prev A
          E += 127 - em;                            // exact bookkeeping
          ex *= __uint_as_float((unsigned)(254 - em) << 23);  // 2^(127-em)
        }
        A = sum * ex;
      }
    }

    // rotate emission buffers; prefetch chunk c0+2 (consumed 8-16 steps later)
#pragma unroll
    for (int r = 0; r < CH; ++r) eC[r] = eN[r];
    const int tb = (t0 + 2 * CH <= SEQN - CH) ? (t0 + 2 * CH) : (SEQN - CH);
#pragma unroll
    for (int r = 0; r < CH; ++r) eN[r] = e_b[(tb + r) * LBL + j];
  }

  // ---- gold path score (lane-strided over t) ----
  float g = 0.0f;
  for (int t = j; t < len; t += 64) {
    const int l = lab_b[t];
    const int prev = (t == 0) ? START_ID : lab_b[t - 1];
    g += T[prev * LBL + l] + e_b[t * LBL + l];
  }

  // ---- final logsumexp + wave reductions ----
  float v = A * expPad;
#pragma unroll
  for (int d = 1; d < 64; d <<= 1) {
    v += __shfl_xor(v, d);
    g += __shfl_xor(g, d);
  }

  if (j == 0) {
    const int last = lab_b[len - 1];
    const float gold = g + T[last * LBL + PAD_ID];
    const float fwd = logf(v) - (float)E * 0.69314718055994531f;
    ws[b] = fwd - gold;
  }
}

__global__ __launch_bounds__(256) void crf_reduce_kernel(
    const float* __restrict__ ws, float* __restrict__ out)
{
  __shared__ float red[4];
  const int tid = threadIdx.x;  // 256 threads
  float v = ws[tid] + ws[tid + 256];
#pragma unroll
  for (int d = 1; d < 64; d <<= 1) v += __shfl_xor(v, d);
  if ((tid & 63) == 0) red[tid >> 6] = v;
  __syncthreads();
  if (tid == 0) out[0] = (red[0] + red[1] + red[2] + red[3]) * (1.0f / BATCHN);
}

extern "C" void kernel_launch(void* const* d_in, const int* in_sizes, int n_in,
                              void* d_out, int out_size, void* d_ws, size_t ws_size,
                              hipStream_t stream) {
  const float* ts      = (const float*)d_in[0];
  const float* T       = (const float*)d_in[1];
  const int*   labels  = (const int*)d_in[2];
  const int*   lengths = (const int*)d_in[3];
  float* out = (float*)d_out;
  float* ws  = (float*)d_ws;

  crf_batch_kernel<<<BATCHN, 64, 0, stream>>>(ts, T, labels, lengths, ws);
  crf_reduce_kernel<<<1, 256, 0, stream>>>(ws, out);
}